// Round 8
// baseline (1966.167 us; speedup 1.0000x reference)
//
#include <hip/hip_runtime.h>

#define TT    512
#define HH    64
#define NB    4
#define NBLK  256        // producer blocks; consumers are NBLK..2*NBLK-1
#define HP    72         // h^T pitch in f16

typedef _Float16 f16x8 __attribute__((ext_vector_type(8)));
typedef _Float16 f16x4 __attribute__((ext_vector_type(4)));
typedef float    f32x4 __attribute__((ext_vector_type(4)));

__device__ __forceinline__ float sigmoidf_(float x) {
    return 1.0f / (1.0f + __expf(-x));
}
__device__ __forceinline__ float tanhf_(float x) {
    return 1.0f - 2.0f / (1.0f + __expf(2.0f * x));
}

struct ProdSmem {
    float    xs[TT * 12];            // x [t][d][4] fp32
    __align__(16) _Float16 h1T[2][16 * HP];
    __align__(16) f32x4    cell[4][64];
};
struct ConsSmem {
    __align__(16) _Float16 h2T[2][16 * HP];
    __align__(16) f32x4    cell[4][64];
    __align__(16) float    h2f[16 * 68];
    float    lg[NB][4];
};
union Smem { ProdSmem p; ConsSmem c; };

// 512 blocks x 256 threads (4 waves each). Blocks [0,256): layer-1 producer
// for 4 batches; blocks [256,512): layer-2 consumer for the same 4 batches.
// Handoff: h1(t) as f16 [t][batch][64] in d_ws (nontemporal stores), progress
// flag per producer published with agent-scope release one tick after the
// data stores (the intervening __syncthreads vmcnt-drains them -> release is
// free). Consumer polls with agent-scope acquire (invalidates stale L2/poison)
// and prefetches h1(t+1) while computing t. Consumer never stalls producer;
// all 512 blocks are co-resident (>=3 blocks/CU capacity at ~45KB LDS).
// Within each block: wave w owns M-tiles {w,w+4,w+8,w+12} (i,f,g,o of units
// [16w,16w+16) in one lane's accumulators); r7's cell transpose gives
// 1 cell/lane pointwise; 1 barrier/tick over only 4 waves.
__global__ __launch_bounds__(256) void lstm_pipe(
    const float* __restrict__ x,
    const float* __restrict__ w_ih0, const float* __restrict__ w_hh0,
    const float* __restrict__ b_ih0, const float* __restrict__ b_hh0,
    const float* __restrict__ w_ih1, const float* __restrict__ w_hh1,
    const float* __restrict__ b_ih1, const float* __restrict__ b_hh1,
    const float* __restrict__ w_out, const float* __restrict__ b_out,
    int* __restrict__ flags, _Float16* __restrict__ h1g,
    float* __restrict__ out)
{
    __shared__ Smem sm;

    const int tid  = threadIdx.x;
    const int w    = tid >> 6;
    const int lane = tid & 63;
    const int quad = lane >> 4;
    const int n    = lane & 15;
    const int cu   = lane >> 2;                     // unit-in-wave after transpose
    const int cb   = lane & 3;                      // batch after transpose
    const int rdslot = lane ^ ((lane >> 4) << 2);   // XOR-swizzled cell slot

    const bool producer = (blockIdx.x < NBLK);

    if (producer) {
        const int b0 = blockIdx.x * NB;
        // ---- weights: W_hh0 fragments + x transform + bias ----
        f16x8 whh[4][2], axf[4];
        f32x4 biasf[4];
        #pragma unroll
        for (int g_ = 0; g_ < 4; ++g_) {
            const int arow = 16 * w + 64 * g_ + n;
            #pragma unroll
            for (int k0 = 0; k0 < 2; ++k0) {
                const float* p = w_hh0 + arow * HH + quad * 8 + 32 * k0;
                #pragma unroll
                for (int j = 0; j < 8; ++j) whh[g_][k0][j] = (_Float16)p[j];
            }
            #pragma unroll
            for (int r = 0; r < 4; ++r) {
                const int crow = 16 * w + 64 * g_ + quad * 4 + r;
                biasf[g_][r] = b_ih0[crow] + b_hh0[crow];
            }
            f16x8 ax;
            #pragma unroll
            for (int j = 0; j < 8; ++j) ax[j] = (_Float16)0.f;
            if (quad == 0) {
                ax[0] = (_Float16)w_ih0[arow * 3 + 0];
                ax[1] = (_Float16)w_ih0[arow * 3 + 1];
                ax[2] = (_Float16)w_ih0[arow * 3 + 2];
            }
            axf[g_] = ax;
        }
        // ---- LDS init ----
        for (int i = tid; i < 1152; i += 256) ((int*)sm.p.h1T)[i] = 0;
        for (int i = tid; i < TT * 12; i += 256) {
            const int t = i / 12, rem = i - t * 12;
            const int d = rem >> 2, b = rem & 3;
            sm.p.xs[i] = x[(size_t)(b0 + b) * (TT * 3) + t * 3 + d];
        }
        __syncthreads();

        float creg = 0.f;
        for (int t = 0; t <= TT + 1; ++t) {
            // publish progress for tick t-2 (its data stores were drained by
            // the barrier at the end of tick t-1; release is then cheap)
            if (tid == 0 && t >= 2)
                __hip_atomic_store(&flags[blockIdx.x], t - 2,
                                   __ATOMIC_RELEASE, __HIP_MEMORY_SCOPE_AGENT);
            if (t < TT) {
                f16x8 bx;
                #pragma unroll
                for (int j = 0; j < 8; ++j) bx[j] = (_Float16)0.f;
                if (quad == 0) {
                    const float* xp = sm.p.xs + t * 12 + (lane & 3);
                    bx[0] = (_Float16)xp[0];
                    bx[1] = (_Float16)xp[4];
                    bx[2] = (_Float16)xp[8];
                }
                const _Float16* hsrc = sm.p.h1T[(t + 1) & 1];
                const f16x8 bh0 = *(const f16x8*)(hsrc + n * HP + quad * 8);
                const f16x8 bh1 = *(const f16x8*)(hsrc + n * HP + quad * 8 + 32);
                f32x4 acc[4];
                #pragma unroll
                for (int g_ = 0; g_ < 4; ++g_) {
                    f32x4 a = __builtin_amdgcn_mfma_f32_16x16x32_f16(axf[g_], bx, biasf[g_], 0, 0, 0);
                    a = __builtin_amdgcn_mfma_f32_16x16x32_f16(whh[g_][0], bh0, a, 0, 0, 0);
                    a = __builtin_amdgcn_mfma_f32_16x16x32_f16(whh[g_][1], bh1, a, 0, 0, 0);
                    acc[g_] = a;
                }
                if (n < 4) {
                    #pragma unroll
                    for (int r = 0; r < 4; ++r) {
                        const int slot = (16 * quad + 4 * r + n) ^ (quad << 2);
                        f32x4 v = {acc[0][r], acc[1][r], acc[2][r], acc[3][r]};
                        sm.p.cell[w][slot] = v;
                    }
                }
                const f32x4 gate = sm.p.cell[w][rdslot];
                const float is = sigmoidf_(gate[0]);
                const float fs = sigmoidf_(gate[1]);
                const float gt = tanhf_(gate[2]);
                const float os = sigmoidf_(gate[3]);
                creg = fs * creg + is * gt;
                sm.p.h1T[t & 1][cb * HP + 16 * w + cu] = (_Float16)(os * tanhf_(creg));
            }
            // wave 0 streams h1(t-1) to global (nontemporal: bypass L2 so the
            // consumer XCD sees it via L3; off the critical path)
            if (w == 0 && t >= 1 && t <= TT && n < 4) {
                const _Float16* hs = sm.p.h1T[(t + 1) & 1];
                f16x8 s0 = *(const f16x8*)(hs + n * HP + quad * 8);
                f16x8 s1 = *(const f16x8*)(hs + n * HP + quad * 8 + 32);
                _Float16* gp = h1g + ((size_t)(t - 1) * 1024 + (size_t)(b0 + n)) * 64;
                __builtin_nontemporal_store(s0, (f16x8*)(gp + quad * 8));
                __builtin_nontemporal_store(s1, (f16x8*)(gp + quad * 8 + 32));
            }
            __syncthreads();
        }
        return;
    }

    // ================= consumer: layer 2 =================
    const int cidx = blockIdx.x - NBLK;
    const int b0 = cidx * NB;
    f16x8 wih[4][2], whh[4][2];
    f32x4 biasf[4];
    #pragma unroll
    for (int g_ = 0; g_ < 4; ++g_) {
        const int arow = 16 * w + 64 * g_ + n;
        #pragma unroll
        for (int k0 = 0; k0 < 2; ++k0) {
            const float* pi = w_ih1 + arow * HH + quad * 8 + 32 * k0;
            const float* ph = w_hh1 + arow * HH + quad * 8 + 32 * k0;
            #pragma unroll
            for (int j = 0; j < 8; ++j) {
                wih[g_][k0][j] = (_Float16)pi[j];
                whh[g_][k0][j] = (_Float16)ph[j];
            }
        }
        #pragma unroll
        for (int r = 0; r < 4; ++r) {
            const int crow = 16 * w + 64 * g_ + quad * 4 + r;
            biasf[g_][r] = b_ih1[crow] + b_hh1[crow];
        }
    }
    for (int i = tid; i < 1152; i += 256) ((int*)sm.c.h2T)[i] = 0;
    __syncthreads();

    const int nb = b0 + (n & 3);          // clamp cols 4..15 onto real batches
    int flagv = -1;
    while (flagv < 0) {
        flagv = __hip_atomic_load(&flags[cidx], __ATOMIC_ACQUIRE, __HIP_MEMORY_SCOPE_AGENT);
        if (flagv < 0) __builtin_amdgcn_s_sleep(8);
    }
    f16x8 cg0, cg1, ng0, ng1;
    {
        const _Float16* gp = h1g + (size_t)nb * 64;     // t2 = 0
        cg0 = *(const f16x8*)(gp + quad * 8);
        cg1 = *(const f16x8*)(gp + quad * 8 + 32);
    }
    float creg = 0.f;
    for (int t2 = 0; t2 < TT; ++t2) {
        const int nx = (t2 + 1 < TT) ? (t2 + 1) : (TT - 1);
        while (flagv < nx) {
            flagv = __hip_atomic_load(&flags[cidx], __ATOMIC_ACQUIRE, __HIP_MEMORY_SCOPE_AGENT);
            if (flagv < nx) __builtin_amdgcn_s_sleep(2);
        }
        {   // prefetch h1(t2+1) while computing t2
            const _Float16* gp = h1g + ((size_t)nx * 1024 + (size_t)nb) * 64;
            ng0 = *(const f16x8*)(gp + quad * 8);
            ng1 = *(const f16x8*)(gp + quad * 8 + 32);
        }
        const _Float16* hsrc = sm.c.h2T[(t2 + 1) & 1];
        const f16x8 bh0 = *(const f16x8*)(hsrc + n * HP + quad * 8);
        const f16x8 bh1 = *(const f16x8*)(hsrc + n * HP + quad * 8 + 32);
        f32x4 acc[4];
        #pragma unroll
        for (int g_ = 0; g_ < 4; ++g_) {
            f32x4 a = __builtin_amdgcn_mfma_f32_16x16x32_f16(wih[g_][0], cg0, biasf[g_], 0, 0, 0);
            a = __builtin_amdgcn_mfma_f32_16x16x32_f16(wih[g_][1], cg1, a, 0, 0, 0);
            a = __builtin_amdgcn_mfma_f32_16x16x32_f16(whh[g_][0], bh0, a, 0, 0, 0);
            a = __builtin_amdgcn_mfma_f32_16x16x32_f16(whh[g_][1], bh1, a, 0, 0, 0);
            acc[g_] = a;
        }
        if (n < 4) {
            #pragma unroll
            for (int r = 0; r < 4; ++r) {
                const int slot = (16 * quad + 4 * r + n) ^ (quad << 2);
                f32x4 v = {acc[0][r], acc[1][r], acc[2][r], acc[3][r]};
                sm.c.cell[w][slot] = v;
            }
        }
        const f32x4 gate = sm.c.cell[w][rdslot];
        const float is = sigmoidf_(gate[0]);
        const float fs = sigmoidf_(gate[1]);
        const float gt = tanhf_(gate[2]);
        const float os = sigmoidf_(gate[3]);
        creg = fs * creg + is * gt;
        const float h = os * tanhf_(creg);
        sm.c.h2T[t2 & 1][cb * HP + 16 * w + cu] = (_Float16)h;
        if (t2 == TT - 1) sm.c.h2f[cb * 68 + 16 * w + cu] = h;
        __syncthreads();
        cg0 = ng0; cg1 = ng1;
    }

    // ---- epilogue: logits + softmax ----
    if (tid < 16) {
        const int b = tid & 3, o = tid >> 2;
        float acc = b_out[o];
        #pragma unroll
        for (int j = 0; j < HH; ++j)
            acc = fmaf(w_out[o * HH + j], sm.c.h2f[b * 68 + j], acc);
        sm.c.lg[b][o] = acc;
    }
    __syncthreads();
    if (tid < NB) {
        const int b = tid;
        const float l0 = sm.c.lg[b][0], l1 = sm.c.lg[b][1];
        const float l2 = sm.c.lg[b][2], l3 = sm.c.lg[b][3];
        const float m  = fmaxf(fmaxf(l0, l1), fmaxf(l2, l3));
        const float e0 = __expf(l0 - m), e1 = __expf(l1 - m);
        const float e2 = __expf(l2 - m), e3 = __expf(l3 - m);
        const float sum = 1.0f / (e0 + e1 + e2 + e3);
        out[(b0 + b) * 4 + 0] = e0 * sum;
        out[(b0 + b) * 4 + 1] = e1 * sum;
        out[(b0 + b) * 4 + 2] = e2 * sum;
        out[(b0 + b) * 4 + 3] = e3 * sum;
    }
}

extern "C" void kernel_launch(void* const* d_in, const int* in_sizes, int n_in,
                              void* d_out, int out_size, void* d_ws, size_t ws_size,
                              hipStream_t stream) {
    const float* x     = (const float*)d_in[0];
    const float* w_ih0 = (const float*)d_in[1];
    const float* w_hh0 = (const float*)d_in[2];
    const float* b_ih0 = (const float*)d_in[3];
    const float* b_hh0 = (const float*)d_in[4];
    const float* w_ih1 = (const float*)d_in[5];
    const float* w_hh1 = (const float*)d_in[6];
    const float* b_ih1 = (const float*)d_in[7];
    const float* b_hh1 = (const float*)d_in[8];
    const float* w_out = (const float*)d_in[9];
    const float* b_out = (const float*)d_in[10];
    float* out = (float*)d_out;

    int*      flags = (int*)d_ws;                                  // 256 ints (poison 0xAA.. < 0)
    _Float16* h1g   = (_Float16*)((char*)d_ws + 4096);             // 64 MB h1 stream

    hipLaunchKernelGGL(lstm_pipe, dim3(2 * NBLK), dim3(256), 0, stream,
                       x, w_ih0, w_hh0, b_ih0, b_hh0,
                       w_ih1, w_hh1, b_ih1, b_hh1,
                       w_out, b_out, flags, h1g, out);
}

// Round 9
// 481.863 us; speedup vs baseline: 4.0803x; 4.0803x over previous
//
#include <hip/hip_runtime.h>

#define TT    512
#define HH    64
#define NB    4
#define NBLK  256
#define HP    72    // h^T pitch in f16

typedef _Float16 f16x8 __attribute__((ext_vector_type(8)));
typedef _Float16 f16x4 __attribute__((ext_vector_type(4)));
typedef float    f32x4 __attribute__((ext_vector_type(4)));

__device__ __forceinline__ float sigmoidf_(float x) {
    return 1.0f / (1.0f + __expf(-x));
}
__device__ __forceinline__ float tanhf_(float x) {
    return 1.0f - 2.0f / (1.0f + __expf(2.0f * x));
}

// 256 blocks x 512 threads (8 waves). Block owns 4 batches (cols 0..3 of the
// 16-col MFMA tile). Group A = waves 0-3 (layer 1), group C = waves 4-7
// (layer 2, FUSED K=128 matvec over [h1; h2] — r8's B group merged away:
// no pis LDS roundtrip, 8 barrier participants instead of 12).
// Wave w of a group owns M-tiles {w,w+4,w+8,w+12} (i,f,g,o of units
// [16w,16w+16) in one lane's accumulators); cell transpose -> 1 cell/lane
// pointwise (r7). One barrier per tick, ticks 0..TT:
//   A (t<TT): g1(t) = b1 + W_ih0 x(t) + W_hh0 h1(t-1) -> h1(t) -> h1T[t&1]
//   C (t>=1): g2 = b2 + W_ih1 h1(t-1) + W_hh1 h2(t-2)  -> h2(t-1) -> h2T[t&1]
// Summation order identical to r7 (bias, ih frags, hh frags) -> same absmax.
// Precision: f16 weights/h-hop, fp32 accum/bias/pointwise/c (r7: 3.9e-3).
// NOTE (r8 lesson): per-tick producer/consumer across blocks = 4x regression
// (agent-scope acquire invalidates the XCD L2). Handoff stays in-block.
__global__ __launch_bounds__(512) void lstm_mfma(
    const float* __restrict__ x,
    const float* __restrict__ w_ih0, const float* __restrict__ w_hh0,
    const float* __restrict__ b_ih0, const float* __restrict__ b_hh0,
    const float* __restrict__ w_ih1, const float* __restrict__ w_hh1,
    const float* __restrict__ b_ih1, const float* __restrict__ b_hh1,
    const float* __restrict__ w_out, const float* __restrict__ b_out,
    float* __restrict__ out)
{
    __shared__ __align__(16) _Float16 h1T[2][16 * HP];  // h1^T [batch][unit] f16
    __shared__ __align__(16) _Float16 h2T[2][16 * HP];  // h2^T
    __shared__ float xs[TT * 12];                       // x [t][d][4] fp32
    __shared__ __align__(16) f32x4 cellA[4][64];        // A gate transpose
    __shared__ __align__(16) f32x4 cellC[4][64];        // C gate transpose
    __shared__ __align__(16) float h2f[16 * 68];        // final h2 fp32
    __shared__ float lg[NB][4];

    const int tid   = threadIdx.x;
    const int group = tid >> 8;          // 0 = A (layer 1), 1 = C (layer 2)
    const int w     = (tid >> 6) & 3;    // wave-in-group
    const int lane  = tid & 63;
    const int quad  = lane >> 4;
    const int n     = lane & 15;         // MFMA column = batch slot
    const int b0    = blockIdx.x * NB;

    const int cu    = lane >> 2;                      // unit after transpose
    const int cb    = lane & 3;                       // batch after transpose
    const int rdslot = lane ^ ((lane >> 4) << 2);     // XOR-swizzled cell slot

    // ---- persistent weight fragments ----
    // A: whh = W_hh0 frags (K=64), axf = x transform;  C: wih = W_ih1, whh = W_hh1
    f16x8 whh[4][2], wih[4][2], axf[4];
    f32x4 biasf[4];
    #pragma unroll
    for (int g_ = 0; g_ < 4; ++g_) {
        const int arow = 16 * w + 64 * g_ + n;        // A-frag row m = lane&15
        const float* ph = (group == 0) ? (w_hh0 + arow * HH) : (w_hh1 + arow * HH);
        const float* pi = w_ih1 + arow * HH;
        #pragma unroll
        for (int k0 = 0; k0 < 2; ++k0) {
            #pragma unroll
            for (int j = 0; j < 8; ++j) {
                whh[g_][k0][j] = (_Float16)ph[quad * 8 + 32 * k0 + j];
                wih[g_][k0][j] = (group == 1) ? (_Float16)pi[quad * 8 + 32 * k0 + j]
                                              : (_Float16)0.f;
            }
        }
        #pragma unroll
        for (int r = 0; r < 4; ++r) {                 // C/D row = quad*4 + r
            const int crow = 16 * w + 64 * g_ + quad * 4 + r;
            biasf[g_][r] = (group == 0) ? (b_ih0[crow] + b_hh0[crow])
                                        : (b_ih1[crow] + b_hh1[crow]);
        }
        f16x8 ax;
        #pragma unroll
        for (int j = 0; j < 8; ++j) ax[j] = (_Float16)0.f;
        if (group == 0 && quad == 0) {                // K=3 x-transform
            ax[0] = (_Float16)w_ih0[arow * 3 + 0];
            ax[1] = (_Float16)w_ih0[arow * 3 + 1];
            ax[2] = (_Float16)w_ih0[arow * 3 + 2];
        }
        axf[g_] = ax;
    }

    // ---- LDS init ----
    for (int i = tid; i < 1152; i += 512) {
        ((int*)h1T)[i] = 0;
        ((int*)h2T)[i] = 0;
    }
    for (int i = tid; i < TT * 12; i += 512) {
        const int t = i / 12, rem = i - t * 12;
        const int d = rem >> 2, b = rem & 3;
        xs[i] = x[(size_t)(b0 + b) * (TT * 3) + t * 3 + d];
    }
    __syncthreads();

    float creg = 0.f;    // A: c1 of (unit 16w+cu, batch cb); C: c2 of same

    for (int t = 0; t <= TT; ++t) {
        if (group == 0) {
            if (t < TT) {
                f16x8 bx;
                #pragma unroll
                for (int j = 0; j < 8; ++j) bx[j] = (_Float16)0.f;
                if (quad == 0) {
                    const float* xp = xs + t * 12 + (lane & 3);
                    bx[0] = (_Float16)xp[0];
                    bx[1] = (_Float16)xp[4];
                    bx[2] = (_Float16)xp[8];
                }
                const _Float16* hsrc = h1T[(t + 1) & 1];
                const f16x8 bh0 = *(const f16x8*)(hsrc + n * HP + quad * 8);
                const f16x8 bh1 = *(const f16x8*)(hsrc + n * HP + quad * 8 + 32);
                f32x4 acc[4];
                #pragma unroll
                for (int g_ = 0; g_ < 4; ++g_) {
                    f32x4 a = __builtin_amdgcn_mfma_f32_16x16x32_f16(axf[g_], bx, biasf[g_], 0, 0, 0);
                    a = __builtin_amdgcn_mfma_f32_16x16x32_f16(whh[g_][0], bh0, a, 0, 0, 0);
                    a = __builtin_amdgcn_mfma_f32_16x16x32_f16(whh[g_][1], bh1, a, 0, 0, 0);
                    acc[g_] = a;
                }
                if (n < 4) {
                    #pragma unroll
                    for (int r = 0; r < 4; ++r) {
                        const int slot = (16 * quad + 4 * r + n) ^ (quad << 2);
                        f32x4 v = {acc[0][r], acc[1][r], acc[2][r], acc[3][r]};
                        cellA[w][slot] = v;
                    }
                }
                const f32x4 gate = cellA[w][rdslot];
                const float is = sigmoidf_(gate[0]);
                const float fs = sigmoidf_(gate[1]);
                const float gt = tanhf_(gate[2]);
                const float os = sigmoidf_(gate[3]);
                creg = fs * creg + is * gt;
                h1T[t & 1][cb * HP + 16 * w + cu] = (_Float16)(os * tanhf_(creg));
            }
        } else {
            if (t >= 1) {
                // fused K=128 matvec over [h1(t-1); h2(t-2)]
                const _Float16* h1src = h1T[(t + 1) & 1];
                const _Float16* h2src = h2T[(t + 1) & 1];
                const f16x8 b10 = *(const f16x8*)(h1src + n * HP + quad * 8);
                const f16x8 b11 = *(const f16x8*)(h1src + n * HP + quad * 8 + 32);
                const f16x8 b20 = *(const f16x8*)(h2src + n * HP + quad * 8);
                const f16x8 b21 = *(const f16x8*)(h2src + n * HP + quad * 8 + 32);
                f32x4 acc[4];
                #pragma unroll
                for (int g_ = 0; g_ < 4; ++g_) {
                    f32x4 a = __builtin_amdgcn_mfma_f32_16x16x32_f16(wih[g_][0], b10, biasf[g_], 0, 0, 0);
                    a = __builtin_amdgcn_mfma_f32_16x16x32_f16(wih[g_][1], b11, a, 0, 0, 0);
                    a = __builtin_amdgcn_mfma_f32_16x16x32_f16(whh[g_][0], b20, a, 0, 0, 0);
                    a = __builtin_amdgcn_mfma_f32_16x16x32_f16(whh[g_][1], b21, a, 0, 0, 0);
                    acc[g_] = a;
                }
                if (n < 4) {
                    #pragma unroll
                    for (int r = 0; r < 4; ++r) {
                        const int slot = (16 * quad + 4 * r + n) ^ (quad << 2);
                        f32x4 v = {acc[0][r], acc[1][r], acc[2][r], acc[3][r]};
                        cellC[w][slot] = v;
                    }
                }
                const f32x4 gate = cellC[w][rdslot];
                const float is = sigmoidf_(gate[0]);
                const float fs = sigmoidf_(gate[1]);
                const float gt = tanhf_(gate[2]);
                const float os = sigmoidf_(gate[3]);
                creg = fs * creg + is * gt;
                const float h = os * tanhf_(creg);
                h2T[t & 1][cb * HP + 16 * w + cu] = (_Float16)h;   // h2(t-1)
                if (t == TT) h2f[cb * 68 + 16 * w + cu] = h;       // h2(TT-1) fp32
            }
        }
        __syncthreads();
    }

    // ---- epilogue: logits + softmax on fp32 h2 ----
    if (tid < 16) {
        const int b = tid & 3, o = tid >> 2;
        float acc = b_out[o];
        #pragma unroll
        for (int j = 0; j < HH; ++j)
            acc = fmaf(w_out[o * HH + j], h2f[b * 68 + j], acc);
        lg[b][o] = acc;
    }
    __syncthreads();
    if (tid < NB) {
        const int b = tid;
        const float l0 = lg[b][0], l1 = lg[b][1], l2 = lg[b][2], l3 = lg[b][3];
        const float m  = fmaxf(fmaxf(l0, l1), fmaxf(l2, l3));
        const float e0 = __expf(l0 - m), e1 = __expf(l1 - m);
        const float e2 = __expf(l2 - m), e3 = __expf(l3 - m);
        const float sum = 1.0f / (e0 + e1 + e2 + e3);
        out[(b0 + b) * 4 + 0] = e0 * sum;
        out[(b0 + b) * 4 + 1] = e1 * sum;
        out[(b0 + b) * 4 + 2] = e2 * sum;
        out[(b0 + b) * 4 + 3] = e3 * sum;
    }
}

extern "C" void kernel_launch(void* const* d_in, const int* in_sizes, int n_in,
                              void* d_out, int out_size, void* d_ws, size_t ws_size,
                              hipStream_t stream) {
    const float* x     = (const float*)d_in[0];
    const float* w_ih0 = (const float*)d_in[1];
    const float* w_hh0 = (const float*)d_in[2];
    const float* b_ih0 = (const float*)d_in[3];
    const float* b_hh0 = (const float*)d_in[4];
    const float* w_ih1 = (const float*)d_in[5];
    const float* w_hh1 = (const float*)d_in[6];
    const float* b_ih1 = (const float*)d_in[7];
    const float* b_hh1 = (const float*)d_in[8];
    const float* w_out = (const float*)d_in[9];
    const float* b_out = (const float*)d_in[10];
    float* out = (float*)d_out;

    hipLaunchKernelGGL(lstm_mfma, dim3(NBLK), dim3(512), 0, stream,
                       x, w_ih0, w_hh0, b_ih0, b_hh0,
                       w_ih1, w_hh1, b_ih1, b_hh1,
                       w_out, b_out, out);
}